// Round 4
// baseline (372.975 us; speedup 1.0000x reference)
//
#include <hip/hip_runtime.h>
#include <hip/hip_bf16.h>
#include <hip/hip_fp16.h>
#include <math.h>

// Problem dims
#define B_   4
#define S_   2048
#define D_   1024
#define H_   16
#define DH_  64
#define M_   (B_ * S_)      // 8192
#define N_   (H_ * DH_)     // 1024

typedef _Float16 f16;
typedef __attribute__((ext_vector_type(2))) _Float16 f16x2;
typedef __attribute__((ext_vector_type(4))) _Float16 f16x4;
typedef __attribute__((ext_vector_type(8))) _Float16 f16x8;
typedef __attribute__((ext_vector_type(4))) float    f32x4;

union H8 { f16x8 v; f16x4 q[2]; f16x2 d[4]; };
union PK { __half2 h2; f16x2 v; };

// device-safe 2^x (glibc's __exp2f is a host symbol — cannot be used)
#if __has_builtin(__builtin_amdgcn_exp2f)
__device__ __forceinline__ float exp2_fast(float x) { return __builtin_amdgcn_exp2f(x); }
#else
__device__ __forceinline__ float exp2_fast(float x) {
  float r; asm("v_exp_f32 %0, %1" : "=v"(r) : "v"(x)); return r;
}
#endif

// ---------------------------------------------------------------------------
// async global -> LDS, 16B per lane. LDS dest must be wave-uniform base;
// HW writes base + lane*16.
__device__ __forceinline__ void async_cp16(const void* g, void* l) {
  __builtin_amdgcn_global_load_lds(
      (const __attribute__((address_space(1))) unsigned int*)g,
      (__attribute__((address_space(3))) unsigned int*)l, 16, 0, 0);
}

// ---------------------------------------------------------------------------
// f32 -> f16 elementwise (vectorized 4-wide)
__global__ __launch_bounds__(256) void cvt_f32_f16(const float* __restrict__ in,
                                                   f16* __restrict__ out, int n4) {
  int i = blockIdx.x * 256 + threadIdx.x;
  if (i < n4) {
    f32x4 v = ((const f32x4*)in)[i];
    ((f16x4*)out)[i] = __builtin_convertvector(v, f16x4);
  }
}

// ---------------------------------------------------------------------------
// Weight transpose+cast: W [1024 x 1024] f32 row-major -> Wt [1024 x 1024] f16
__global__ __launch_bounds__(256) void transpose_w(
    const float* __restrict__ W0, const float* __restrict__ W1,
    const float* __restrict__ W2, const float* __restrict__ W3,
    f16* __restrict__ T0, f16* __restrict__ T1,
    f16* __restrict__ T2, f16* __restrict__ T3) {
  const float* W = (blockIdx.z == 0) ? W0 : (blockIdx.z == 1) ? W1
                 : (blockIdx.z == 2) ? W2 : W3;
  f16* T = (blockIdx.z == 0) ? T0 : (blockIdx.z == 1) ? T1
         : (blockIdx.z == 2) ? T2 : T3;
  __shared__ float tile[32][33];
  int x  = blockIdx.x * 32 + threadIdx.x;
  int y0 = blockIdx.y * 32 + threadIdx.y;
#pragma unroll
  for (int i = 0; i < 32; i += 8)
    tile[threadIdx.y + i][threadIdx.x] = W[(size_t)(y0 + i) * 1024 + x];
  __syncthreads();
  int tx  = blockIdx.y * 32 + threadIdx.x;
  int ty0 = blockIdx.x * 32 + threadIdx.y;
#pragma unroll
  for (int i = 0; i < 32; i += 8)
    T[(size_t)(ty0 + i) * 1024 + tx] = (f16)tile[threadIdx.x][threadIdx.y + i];
}

// ---------------------------------------------------------------------------
// v [B,S,H,DH] f16  ->  vt [B,H,DH,S] f16
__global__ __launch_bounds__(256) void transpose_v(const f16* __restrict__ v,
                                                   f16* __restrict__ vt) {
  int bh = blockIdx.y;
  int b  = bh >> 4, h = bh & 15;
  int s0 = blockIdx.x * 64;
  __shared__ f16 tile[64][72];
  int tid = threadIdx.x;
#pragma unroll
  for (int it = 0; it < 16; ++it) {
    int idx = it * 256 + tid;
    int r = idx >> 6, c = idx & 63;
    tile[r][c] = v[((size_t)(b * S_ + s0 + r)) * N_ + h * DH_ + c];
  }
  __syncthreads();
#pragma unroll
  for (int it = 0; it < 16; ++it) {
    int idx = it * 256 + tid;
    int fr = idx >> 6, sc = idx & 63;
    vt[((size_t)bh * DH_ + fr) * S_ + s0 + sc] = tile[sc][fr];
  }
}

// ---------------------------------------------------------------------------
// Fused QKV GEMM: out_p[M,1024] = A_p[M,1024] * WtT_p^T  for p in {q,k,v}.
// A_q = inq, A_k = A_v = inkv. 128x128 tile, BK=64, 256 threads (2x2 waves),
// double-buffered LDS (2-phase: prefetch t+1 while computing t, ONE barrier
// per K-step so the vmcnt drain lands after the MFMA phase).
// Grid: 64 m-tiles x 24 n-tiles = 1536 (%8==0 for bijective XCD swizzle).
__global__ __launch_bounds__(256) void gemm_qkv(
    const f16* __restrict__ Aq, const f16* __restrict__ Akv,
    const f16* __restrict__ WqT, const f16* __restrict__ WkT, const f16* __restrict__ WvT,
    const float* __restrict__ bq, const float* __restrict__ bk, const float* __restrict__ bv,
    float qscale, f16* __restrict__ oq, f16* __restrict__ ok, f16* __restrict__ ov) {
  __shared__ f16 lA[2][128 * 64];
  __shared__ f16 lB[2][128 * 64];
  const int cpx = gridDim.x >> 3;
  const int wg  = (blockIdx.x & 7) * cpx + (blockIdx.x >> 3);
  const int tile_m = (wg / 24) * 128;
  const int nt = wg % 24, part = nt >> 3;
  const int tile_n = (nt & 7) * 128;
  const f16* A  = (part == 0) ? Aq : Akv;
  const f16* Bt = ((part == 0) ? WqT : (part == 1) ? WkT : WvT) + (size_t)tile_n * D_;
  const float* bias = ((part == 0) ? bq : (part == 1) ? bk : bv) + tile_n;
  f16* outp = ((part == 0) ? oq : (part == 1) ? ok : ov);
  const float scale = (part == 0) ? qscale : 1.0f;

  const int tid  = threadIdx.x;
  const int lane = tid & 63, wid = tid >> 6;
  const int wr = wid >> 1, wc = wid & 1;
  const int l8 = lane >> 3, c8 = (lane & 7) * 8;
  const int r15 = lane & 15, hi = lane >> 4;

  f32x4 acc[4][4];
#pragma unroll
  for (int m = 0; m < 4; ++m)
#pragma unroll
    for (int n = 0; n < 4; ++n) acc[m][n] = (f32x4)(0.f);

  auto STAGE = [&](int t, int buf) {
    int kt = t * 64;
#pragma unroll
    for (int i = 0; i < 4; ++i) {
      int rb = wid * 32 + i * 8;
      async_cp16(A  + (size_t)(tile_m + rb + l8) * D_ + kt + c8, &lA[buf][rb * 64]);
      async_cp16(Bt + (size_t)(rb + l8) * D_ + kt + c8, &lB[buf][rb * 64]);
    }
  };

  STAGE(0, 0);
  __syncthreads();
  for (int t = 0; t < D_ / 64; ++t) {
    const int cur = t & 1;
    if (t + 1 < D_ / 64) STAGE(t + 1, cur ^ 1);
#pragma unroll
    for (int kk = 0; kk < 2; ++kk) {
      f16x8 af[4], bf[4];
#pragma unroll
      for (int m = 0; m < 4; ++m)
        af[m] = *(const f16x8*)&lA[cur][(wr * 64 + m * 16 + r15) * 64 + kk * 32 + hi * 8];
#pragma unroll
      for (int n = 0; n < 4; ++n)
        bf[n] = *(const f16x8*)&lB[cur][(wc * 64 + n * 16 + r15) * 64 + kk * 32 + hi * 8];
#pragma unroll
      for (int m = 0; m < 4; ++m)
#pragma unroll
        for (int n = 0; n < 4; ++n)
          acc[m][n] = __builtin_amdgcn_mfma_f32_16x16x32_f16(af[m], bf[n], acc[m][n], 0, 0, 0);
    }
    __syncthreads();
  }

#pragma unroll
  for (int m = 0; m < 4; ++m) {
    int row0 = tile_m + wr * 64 + m * 16 + hi * 4;
#pragma unroll
    for (int n = 0; n < 4; ++n) {
      int col = wc * 64 + n * 16 + r15;
      float bv_ = bias[col];
#pragma unroll
      for (int r = 0; r < 4; ++r) {
        float v = (acc[m][n][r] + bv_) * scale;
        outp[(size_t)(row0 + r) * N_ + tile_n + col] = (f16)v;
      }
    }
  }
}

// ---------------------------------------------------------------------------
// Output-projection GEMM: C[M,N] = A[M,K]*Bt[N,K]^T + bias, f32 out.
// Same 2-phase double-buffered structure.
__global__ __launch_bounds__(256) void gemm_out(
    const f16* __restrict__ A, const f16* __restrict__ Bt,
    const float* __restrict__ bias, float* __restrict__ outp,
    int M, int N, int K) {
  __shared__ f16 lA[2][128 * 64];
  __shared__ f16 lB[2][128 * 64];
  const int nbx = N >> 7;
  const int cpx = gridDim.x >> 3;
  const int wg  = (blockIdx.x & 7) * cpx + (blockIdx.x >> 3);
  const int tile_m = (wg / nbx) * 128, tile_n = (wg % nbx) * 128;
  const int tid  = threadIdx.x;
  const int lane = tid & 63, wid = tid >> 6;
  const int wr = wid >> 1, wc = wid & 1;
  const int l8 = lane >> 3, c8 = (lane & 7) * 8;
  const int r15 = lane & 15, hi = lane >> 4;

  f32x4 acc[4][4];
#pragma unroll
  for (int m = 0; m < 4; ++m)
#pragma unroll
    for (int n = 0; n < 4; ++n) acc[m][n] = (f32x4)(0.f);

  auto STAGE = [&](int t, int buf) {
    int kt = t * 64;
#pragma unroll
    for (int i = 0; i < 4; ++i) {
      int rb = wid * 32 + i * 8;
      async_cp16(A  + (size_t)(tile_m + rb + l8) * K + kt + c8, &lA[buf][rb * 64]);
      async_cp16(Bt + (size_t)(tile_n + rb + l8) * K + kt + c8, &lB[buf][rb * 64]);
    }
  };

  STAGE(0, 0);
  __syncthreads();
  const int T = K / 64;
  for (int t = 0; t < T; ++t) {
    const int cur = t & 1;
    if (t + 1 < T) STAGE(t + 1, cur ^ 1);
#pragma unroll
    for (int kk = 0; kk < 2; ++kk) {
      f16x8 af[4], bf[4];
#pragma unroll
      for (int m = 0; m < 4; ++m)
        af[m] = *(const f16x8*)&lA[cur][(wr * 64 + m * 16 + r15) * 64 + kk * 32 + hi * 8];
#pragma unroll
      for (int n = 0; n < 4; ++n)
        bf[n] = *(const f16x8*)&lB[cur][(wc * 64 + n * 16 + r15) * 64 + kk * 32 + hi * 8];
#pragma unroll
      for (int m = 0; m < 4; ++m)
#pragma unroll
        for (int n = 0; n < 4; ++n)
          acc[m][n] = __builtin_amdgcn_mfma_f32_16x16x32_f16(af[m], bf[n], acc[m][n], 0, 0, 0);
    }
    __syncthreads();
  }

#pragma unroll
  for (int m = 0; m < 4; ++m) {
    int row0 = tile_m + wr * 64 + m * 16 + hi * 4;
#pragma unroll
    for (int n = 0; n < 4; ++n) {
      int col = tile_n + wc * 64 + n * 16 + r15;
      float bv = bias[col];
#pragma unroll
      for (int r = 0; r < 4; ++r)
        outp[(size_t)(row0 + r) * N + col] = acc[m][n][r] + bv;
    }
  }
}

// ---------------------------------------------------------------------------
// Flash attention, fully-swapped operands (see round-3 comments).
// Adds: T13 defer-max (skip xa-rescale when tile max grew <= 8 in log2
// domain), T5 s_setprio around MFMA clusters.
__global__ __launch_bounds__(256, 2) void attn(
    const f16* __restrict__ q, const f16* __restrict__ k,
    const f16* __restrict__ vt, f16* __restrict__ x) {
  __shared__ f16 lK[2][64 * 64];
  __shared__ f16 lV[2][64 * 64];
  const int tid = threadIdx.x, lane = tid & 63, wid = tid >> 6;
  const int bh = blockIdx.y, b = bh >> 4, h = bh & 15;
  const int q0 = blockIdx.x * 256 + wid * 64;
  const int c15 = lane & 15, hi = lane >> 4;
  const int swr = (c15 & 7) << 4;                 // read-side XOR (bytes)
  const int swz = 8 * ((lane & 7) ^ (lane >> 3)); // staging source col (elems)
  const int lrow = lane >> 3;                     // staging source row in chunk

  const f16* qb = q  + (size_t)b * S_ * N_ + h * DH_;
  const f16* kb = k  + (size_t)b * S_ * N_ + h * DH_;
  const f16* vb = vt + (size_t)bh * DH_ * S_;

  f16x8 qf[4][2];
#pragma unroll
  for (int qm = 0; qm < 4; ++qm)
#pragma unroll
    for (int kk = 0; kk < 2; ++kk)
      qf[qm][kk] = *(const f16x8*)(qb + (size_t)(q0 + qm * 16 + c15) * N_ + kk * 32 + hi * 8);

  f32x4 xa[4][4];   // [fn][qm], x^T: rows f, cols q
#pragma unroll
  for (int fn = 0; fn < 4; ++fn)
#pragma unroll
    for (int qm = 0; qm < 4; ++qm) xa[fn][qm] = (f32x4)(0.f);
  float rm[4], rl[4];
#pragma unroll
  for (int qm = 0; qm < 4; ++qm) { rm[qm] = -INFINITY; rl[qm] = 0.f; }

  auto STAGE = [&](int t, int buf) {
    int j0 = t * 64;
#pragma unroll
    for (int i = 0; i < 2; ++i) {
      int rb = wid * 16 + i * 8;
      async_cp16(kb + (size_t)(j0 + rb + lrow) * N_ + swz, &lK[buf][rb * 64]);
      async_cp16(vb + (size_t)(rb + lrow) * S_ + j0 + swz, &lV[buf][rb * 64]);
    }
  };

  STAGE(0, 0);
  __syncthreads();

  for (int t = 0; t < S_ / 64; ++t) {
    const int cur = t & 1;
    if (t < S_ / 64 - 1) STAGE(t + 1, cur ^ 1);

    f16x8 kf[4][2];
#pragma unroll
    for (int jn = 0; jn < 4; ++jn) {
      int rowe = (jn * 16 + c15) * 64;
#pragma unroll
      for (int kk = 0; kk < 2; ++kk)
        kf[jn][kk] = *(const f16x8*)&lK[cur][rowe + (((kk * 64 + hi * 16) ^ swr) >> 1)];
    }

    f16x8 bfrag[4][2];
#pragma unroll
    for (int qm = 0; qm < 4; ++qm) {
      f32x4 sq[4];
#pragma unroll
      for (int jn = 0; jn < 4; ++jn) sq[jn] = (f32x4)(0.f);
      __builtin_amdgcn_s_setprio(1);
#pragma unroll
      for (int kk = 0; kk < 2; ++kk)
#pragma unroll
        for (int jn = 0; jn < 4; ++jn)
          sq[jn] = __builtin_amdgcn_mfma_f32_16x16x32_f16(kf[jn][kk], qf[qm][kk], sq[jn], 0, 0, 0);
      __builtin_amdgcn_s_setprio(0);

      float mx = sq[0][0];
#pragma unroll
      for (int jn = 0; jn < 4; ++jn)
#pragma unroll
        for (int r = 0; r < 4; ++r) mx = fmaxf(mx, sq[jn][r]);
      mx = fmaxf(mx, __shfl_xor(mx, 16));
      mx = fmaxf(mx, __shfl_xor(mx, 32));

      // T13 defer-max: if tile max didn't grow past rm+8, keep rm (fac=1,
      // skip the xa rescale). First tile: rm=-inf -> condition false.
      float p[4][4], ts = 0.f;
      if (__all(mx - rm[qm] <= 8.0f)) {
#pragma unroll
        for (int jn = 0; jn < 4; ++jn)
#pragma unroll
          for (int r = 0; r < 4; ++r) {
            p[jn][r] = exp2_fast(sq[jn][r] - rm[qm]);
            ts += p[jn][r];
          }
        ts += __shfl_xor(ts, 16);
        ts += __shfl_xor(ts, 32);
        rl[qm] += ts;
      } else {
        float nm  = fmaxf(rm[qm], mx);
        float fac = exp2_fast(rm[qm] - nm);
        rm[qm] = nm;
#pragma unroll
        for (int jn = 0; jn < 4; ++jn)
#pragma unroll
          for (int r = 0; r < 4; ++r) {
            p[jn][r] = exp2_fast(sq[jn][r] - nm);
            ts += p[jn][r];
          }
        ts += __shfl_xor(ts, 16);
        ts += __shfl_xor(ts, 32);
        rl[qm] = rl[qm] * fac + ts;
#pragma unroll
        for (int fn = 0; fn < 4; ++fn)
#pragma unroll
          for (int r = 0; r < 4; ++r) xa[fn][qm][r] *= fac;
      }

      PK w[4][2];
#pragma unroll
      for (int jn = 0; jn < 4; ++jn)
#pragma unroll
        for (int hh = 0; hh < 2; ++hh)
          w[jn][hh].h2 = __floats2half2_rn(p[jn][2 * hh], p[jn][2 * hh + 1]);
#pragma unroll
      for (int kk = 0; kk < 2; ++kk) {
        H8 u;
        u.d[0] = w[2 * kk][0].v;     u.d[1] = w[2 * kk][1].v;
        u.d[2] = w[2 * kk + 1][0].v; u.d[3] = w[2 * kk + 1][1].v;
        bfrag[qm][kk] = u.v;
      }
    }

    // PV: x^T += Vt * P.
    __builtin_amdgcn_s_setprio(1);
#pragma unroll
    for (int kk = 0; kk < 2; ++kk)
#pragma unroll
      for (int fn = 0; fn < 4; ++fn) {
        int rowe = (fn * 16 + c15) * 64;
        H8 u;
        u.q[0] = *(const f16x4*)&lV[cur][rowe + (((kk * 64 + hi * 8) ^ swr) >> 1)];
        u.q[1] = *(const f16x4*)&lV[cur][rowe + (((kk * 64 + 32 + hi * 8) ^ swr) >> 1)];
#pragma unroll
        for (int qm = 0; qm < 4; ++qm)
          xa[fn][qm] = __builtin_amdgcn_mfma_f32_16x16x32_f16(u.v, bfrag[qm][kk], xa[fn][qm], 0, 0, 0);
      }
    __builtin_amdgcn_s_setprio(0);
    __syncthreads();
  }

  float inv[4];
#pragma unroll
  for (int qm = 0; qm < 4; ++qm) inv[qm] = 1.f / rl[qm];
#pragma unroll
  for (int qm = 0; qm < 4; ++qm) {
    size_t rowb = (size_t)(b * S_ + q0 + qm * 16 + c15) * N_ + h * DH_;
#pragma unroll
    for (int fn = 0; fn < 4; ++fn) {
      f16x4 o;
#pragma unroll
      for (int r = 0; r < 4; ++r) o[r] = (f16)(xa[fn][qm][r] * inv[qm]);
      *(f16x4*)(x + rowb + fn * 16 + hi * 4) = o;
    }
  }
}

// ---------------------------------------------------------------------------
extern "C" void kernel_launch(void* const* d_in, const int* in_sizes, int n_in,
                              void* d_out, int out_size, void* d_ws, size_t ws_size,
                              hipStream_t stream) {
  const float* inq  = (const float*)d_in[0];
  const float* inkv = (const float*)d_in[1];
  const float* Wq = (const float*)d_in[2];
  const float* bq = (const float*)d_in[3];
  const float* Wk = (const float*)d_in[4];
  const float* bk = (const float*)d_in[5];
  const float* Wv = (const float*)d_in[6];
  const float* bv = (const float*)d_in[7];
  const float* Wo = (const float*)d_in[8];
  const float* bo = (const float*)d_in[9];
  float* out = (float*)d_out;

  char* ws = (char*)d_ws;
  const size_t MB = 1024 * 1024;
  f16* h_inq  = (f16*)(ws + 0);         // 16MB, later reused as vt
  f16* h_inkv = (f16*)(ws + 16 * MB);   // 16MB, later reused as x
  f16* h_WqT  = (f16*)(ws + 32 * MB);
  f16* h_WkT  = (f16*)(ws + 34 * MB);
  f16* h_WvT  = (f16*)(ws + 36 * MB);
  f16* h_WoT  = (f16*)(ws + 38 * MB);
  f16* h_q    = (f16*)(ws + 40 * MB);
  f16* h_k    = (f16*)(ws + 56 * MB);
  f16* h_v    = (f16*)(ws + 72 * MB);
  f16* h_vt   = h_inq;                  // alias (inq dead after QKV GEMM)
  f16* h_x    = h_inkv;                 // alias (inkv dead after QKV GEMM)

  const int nIn = M_ * D_;
  cvt_f32_f16<<<nIn / 4 / 256, 256, 0, stream>>>(inq,  h_inq,  nIn / 4);
  cvt_f32_f16<<<nIn / 4 / 256, 256, 0, stream>>>(inkv, h_inkv, nIn / 4);
  transpose_w<<<dim3(32, 32, 4), dim3(32, 8), 0, stream>>>(
      Wq, Wk, Wv, Wo, h_WqT, h_WkT, h_WvT, h_WoT);
  // q scale folds 1/sqrt(DH) and log2(e) for the exp2-domain softmax
  const float qscale = 0.125f * 1.4426950408889634f;
  // fused QKV: 64 m-tiles x 24 n-tiles = 1536 WGs (%8==0)
  gemm_qkv<<<1536, 256, 0, stream>>>(h_inq, h_inkv, h_WqT, h_WkT, h_WvT,
                                     bq, bk, bv, qscale, h_q, h_k, h_v);
  transpose_v<<<dim3(S_ / 64, B_ * H_), 256, 0, stream>>>(h_v, h_vt);
  attn<<<dim3(S_ / 256, B_ * H_), 256, 0, stream>>>(h_q, h_k, h_vt, h_x);
  gemm_out<<<(M_ / 128) * (N_ / 128), 256, 0, stream>>>(h_x, h_WoT, bo, out, M_, N_, D_);
}

// Round 6
// 340.569 us; speedup vs baseline: 1.0952x; 1.0952x over previous
//
#include <hip/hip_runtime.h>
#include <hip/hip_bf16.h>
#include <hip/hip_fp16.h>
#include <math.h>

// Problem dims
#define B_   4
#define S_   2048
#define D_   1024
#define H_   16
#define DH_  64
#define M_   (B_ * S_)      // 8192
#define N_   (H_ * DH_)     // 1024

typedef _Float16 f16;
typedef __attribute__((ext_vector_type(2))) _Float16 f16x2;
typedef __attribute__((ext_vector_type(4))) _Float16 f16x4;
typedef __attribute__((ext_vector_type(8))) _Float16 f16x8;
typedef __attribute__((ext_vector_type(4))) float    f32x4;

union H8 { f16x8 v; f16x4 q[2]; f16x2 d[4]; };
union PK { __half2 h2; f16x2 v; };

// device-safe 2^x (glibc's __exp2f is a host symbol — cannot be used)
#if __has_builtin(__builtin_amdgcn_exp2f)
__device__ __forceinline__ float exp2_fast(float x) { return __builtin_amdgcn_exp2f(x); }
#else
__device__ __forceinline__ float exp2_fast(float x) {
  float r; asm("v_exp_f32 %0, %1" : "=v"(r) : "v"(x)); return r;
}
#endif

// ---------------------------------------------------------------------------
// async global -> LDS, 16B per lane. LDS dest must be wave-uniform base;
// HW writes base + lane*16.
__device__ __forceinline__ void async_cp16(const void* g, void* l) {
  __builtin_amdgcn_global_load_lds(
      (const __attribute__((address_space(1))) unsigned int*)g,
      (__attribute__((address_space(3))) unsigned int*)l, 16, 0, 0);
}

// ---------------------------------------------------------------------------
// f32 -> f16 elementwise (vectorized 4-wide)
__global__ __launch_bounds__(256) void cvt_f32_f16(const float* __restrict__ in,
                                                   f16* __restrict__ out, int n4) {
  int i = blockIdx.x * 256 + threadIdx.x;
  if (i < n4) {
    f32x4 v = ((const f32x4*)in)[i];
    ((f16x4*)out)[i] = __builtin_convertvector(v, f16x4);
  }
}

// ---------------------------------------------------------------------------
// Weight transpose+cast: W [1024 x 1024] f32 row-major -> Wt [1024 x 1024] f16
__global__ __launch_bounds__(256) void transpose_w(
    const float* __restrict__ W0, const float* __restrict__ W1,
    const float* __restrict__ W2, const float* __restrict__ W3,
    f16* __restrict__ T0, f16* __restrict__ T1,
    f16* __restrict__ T2, f16* __restrict__ T3) {
  const float* W = (blockIdx.z == 0) ? W0 : (blockIdx.z == 1) ? W1
                 : (blockIdx.z == 2) ? W2 : W3;
  f16* T = (blockIdx.z == 0) ? T0 : (blockIdx.z == 1) ? T1
         : (blockIdx.z == 2) ? T2 : T3;
  __shared__ float tile[32][33];
  int x  = blockIdx.x * 32 + threadIdx.x;
  int y0 = blockIdx.y * 32 + threadIdx.y;
#pragma unroll
  for (int i = 0; i < 32; i += 8)
    tile[threadIdx.y + i][threadIdx.x] = W[(size_t)(y0 + i) * 1024 + x];
  __syncthreads();
  int tx  = blockIdx.y * 32 + threadIdx.x;
  int ty0 = blockIdx.x * 32 + threadIdx.y;
#pragma unroll
  for (int i = 0; i < 32; i += 8)
    T[(size_t)(ty0 + i) * 1024 + tx] = (f16)tile[threadIdx.x][threadIdx.y + i];
}

// ---------------------------------------------------------------------------
// v [B,S,H,DH] f16  ->  vt [B,H,DH,S] f16
__global__ __launch_bounds__(256) void transpose_v(const f16* __restrict__ v,
                                                   f16* __restrict__ vt) {
  int bh = blockIdx.y;
  int b  = bh >> 4, h = bh & 15;
  int s0 = blockIdx.x * 64;
  __shared__ f16 tile[64][72];
  int tid = threadIdx.x;
#pragma unroll
  for (int it = 0; it < 16; ++it) {
    int idx = it * 256 + tid;
    int r = idx >> 6, c = idx & 63;
    tile[r][c] = v[((size_t)(b * S_ + s0 + r)) * N_ + h * DH_ + c];
  }
  __syncthreads();
#pragma unroll
  for (int it = 0; it < 16; ++it) {
    int idx = it * 256 + tid;
    int fr = idx >> 6, sc = idx & 63;
    vt[((size_t)bh * DH_ + fr) * S_ + s0 + sc] = tile[sc][fr];
  }
}

// ===========================================================================
// Deep-pipelined GEMM (T3/T4/T5): BM=128, BN=256, BK=32, 512 thr (8 waves
// as 2Mx4N, per-wave 64x64 out). 3-slot LDS ring (72KB -> 2 blocks/CU).
// Schedule per K-tile c: {ds_read frags of slot c%3 | stage K-tile c+2 into
// slot (c+2)%3 | s_waitcnt vmcnt(3) (c+1 landed; c+2's 3 loads in flight) |
// s_barrier | setprio(1) 16 MFMA setprio(0) | s_barrier}. vmcnt never drains
// to 0 mid-loop. Ring safety: slot (c+2)%3 last read during K-tile c-1;
// every wave's reads complete before its exit barrier of c-1, and the stage
// issues after that barrier.
// LDS swizzle: 8-elem slot ^= (row>>1)&3, matched pre-swizzled global source
// (rule 21). Frag reads then hit 2 lanes/bank = conflict-free.
// ===========================================================================

// Fused QKV: A_q=inq, A_k=A_v=inkv. WqkvT = concat [3072][1024] f16 (q,k,v).
// Grid: 64 m-tiles x 12 n-tiles = 768 (%8==0 for XCD swizzle).
__global__ __launch_bounds__(512, 4) void gemm_qkv8(
    const f16* __restrict__ Aq, const f16* __restrict__ Akv,
    const f16* __restrict__ WqkvT,
    const float* __restrict__ bq, const float* __restrict__ bk, const float* __restrict__ bv,
    float qscale, f16* __restrict__ oq, f16* __restrict__ ok, f16* __restrict__ ov) {
  __shared__ f16 lA[3][128 * 32];
  __shared__ f16 lB[3][256 * 32];
  const int cpx = gridDim.x >> 3;
  const int wg  = (blockIdx.x & 7) * cpx + (blockIdx.x >> 3);
  const int tile_m = (wg / 12) * 128;
  const int nt = wg % 12, part = nt >> 2, tile_np = (nt & 3) * 256;
  const f16* A  = (part == 0) ? Aq : Akv;
  const f16* Bt = WqkvT + ((size_t)part << 20) + (size_t)tile_np * 1024;
  const float* bias = ((part == 0) ? bq : (part == 1) ? bk : bv) + tile_np;
  f16* outp = (part == 0) ? oq : (part == 1) ? ok : ov;
  const float scale = (part == 0) ? qscale : 1.0f;

  const int tid = threadIdx.x, lane = tid & 63, wid = tid >> 6;
  const int wr = wid >> 2, wc = wid & 3;
  const int r15 = lane & 15, hi = lane >> 4;
  const int srow = lane >> 2;                        // row within 16-row chunk
  const int scol = 8 * ((lane & 3) ^ ((lane >> 3) & 3));  // pre-swizzled src slot
  const int fslot = 8 * (hi ^ ((r15 >> 1) & 3));     // swizzled read slot

  const f16* sA  = A  + (size_t)(tile_m + wid * 16 + srow) * 1024 + scol;
  const f16* sB0 = Bt + (size_t)(wid * 16 + srow) * 1024 + scol;
  const f16* sB1 = sB0 + (size_t)128 * 1024;

  f32x4 acc[4][4];
#pragma unroll
  for (int m = 0; m < 4; ++m)
#pragma unroll
    for (int n = 0; n < 4; ++n) acc[m][n] = (f32x4)(0.f);

  auto STAGE = [&](int t, int sl) {
    async_cp16(sA  + t * 32, &lA[sl][wid * 512]);
    async_cp16(sB0 + t * 32, &lB[sl][wid * 512]);
    async_cp16(sB1 + t * 32, &lB[sl][4096 + wid * 512]);
  };

  STAGE(0, 0);
  STAGE(1, 1);
  asm volatile("s_waitcnt vmcnt(3)" ::: "memory");
  __builtin_amdgcn_s_barrier();

  int s = 0;
  for (int c = 0; c < 32; ++c) {
    f16x8 af[4], bf[4];
#pragma unroll
    for (int m = 0; m < 4; ++m)
      af[m] = *(const f16x8*)&lA[s][(wr * 64 + m * 16 + r15) * 32 + fslot];
#pragma unroll
    for (int n = 0; n < 4; ++n)
      bf[n] = *(const f16x8*)&lB[s][(wc * 64 + n * 16 + r15) * 32 + fslot];
    if (c + 2 < 32) {
      int s2 = s + 2; if (s2 >= 3) s2 -= 3;
      STAGE(c + 2, s2);
      asm volatile("s_waitcnt vmcnt(3)" ::: "memory");
    } else {
      asm volatile("s_waitcnt vmcnt(0)" ::: "memory");
    }
    __builtin_amdgcn_s_barrier();
    __builtin_amdgcn_s_setprio(1);
#pragma unroll
    for (int m = 0; m < 4; ++m)
#pragma unroll
      for (int n = 0; n < 4; ++n)
        acc[m][n] = __builtin_amdgcn_mfma_f32_16x16x32_f16(af[m], bf[n], acc[m][n], 0, 0, 0);
    __builtin_amdgcn_s_setprio(0);
    __builtin_amdgcn_s_barrier();
    ++s; if (s == 3) s = 0;
  }

#pragma unroll
  for (int m = 0; m < 4; ++m) {
    int row0 = tile_m + wr * 64 + m * 16 + hi * 4;
#pragma unroll
    for (int n = 0; n < 4; ++n) {
      int col = wc * 64 + n * 16 + r15;
      float bv_ = bias[col];
#pragma unroll
      for (int r = 0; r < 4; ++r) {
        float v = (acc[m][n][r] + bv_) * scale;
        outp[(size_t)(row0 + r) * N_ + tile_np + col] = (f16)v;
      }
    }
  }
}

// Output projection: out[M,1024] = x[M,1024]*WoT^T + bo, f32 out.
// Grid: 64 m-tiles x 4 n-tiles = 256 (%8==0).
__global__ __launch_bounds__(512, 4) void gemm_out8(
    const f16* __restrict__ A, const f16* __restrict__ Bt,
    const float* __restrict__ bias, float* __restrict__ outp) {
  __shared__ f16 lA[3][128 * 32];
  __shared__ f16 lB[3][256 * 32];
  const int cpx = gridDim.x >> 3;
  const int wg  = (blockIdx.x & 7) * cpx + (blockIdx.x >> 3);
  const int tile_m = (wg >> 2) * 128;
  const int tile_n = (wg & 3) * 256;

  const int tid = threadIdx.x, lane = tid & 63, wid = tid >> 6;
  const int wr = wid >> 2, wc = wid & 3;
  const int r15 = lane & 15, hi = lane >> 4;
  const int srow = lane >> 2;
  const int scol = 8 * ((lane & 3) ^ ((lane >> 3) & 3));
  const int fslot = 8 * (hi ^ ((r15 >> 1) & 3));

  const f16* sA  = A  + (size_t)(tile_m + wid * 16 + srow) * 1024 + scol;
  const f16* sB0 = Bt + (size_t)(tile_n + wid * 16 + srow) * 1024 + scol;
  const f16* sB1 = sB0 + (size_t)128 * 1024;

  f32x4 acc[4][4];
#pragma unroll
  for (int m = 0; m < 4; ++m)
#pragma unroll
    for (int n = 0; n < 4; ++n) acc[m][n] = (f32x4)(0.f);

  auto STAGE = [&](int t, int sl) {
    async_cp16(sA  + t * 32, &lA[sl][wid * 512]);
    async_cp16(sB0 + t * 32, &lB[sl][wid * 512]);
    async_cp16(sB1 + t * 32, &lB[sl][4096 + wid * 512]);
  };

  STAGE(0, 0);
  STAGE(1, 1);
  asm volatile("s_waitcnt vmcnt(3)" ::: "memory");
  __builtin_amdgcn_s_barrier();

  int s = 0;
  for (int c = 0; c < 32; ++c) {
    f16x8 af[4], bf[4];
#pragma unroll
    for (int m = 0; m < 4; ++m)
      af[m] = *(const f16x8*)&lA[s][(wr * 64 + m * 16 + r15) * 32 + fslot];
#pragma unroll
    for (int n = 0; n < 4; ++n)
      bf[n] = *(const f16x8*)&lB[s][(wc * 64 + n * 16 + r15) * 32 + fslot];
    if (c + 2 < 32) {
      int s2 = s + 2; if (s2 >= 3) s2 -= 3;
      STAGE(c + 2, s2);
      asm volatile("s_waitcnt vmcnt(3)" ::: "memory");
    } else {
      asm volatile("s_waitcnt vmcnt(0)" ::: "memory");
    }
    __builtin_amdgcn_s_barrier();
    __builtin_amdgcn_s_setprio(1);
#pragma unroll
    for (int m = 0; m < 4; ++m)
#pragma unroll
      for (int n = 0; n < 4; ++n)
        acc[m][n] = __builtin_amdgcn_mfma_f32_16x16x32_f16(af[m], bf[n], acc[m][n], 0, 0, 0);
    __builtin_amdgcn_s_setprio(0);
    __builtin_amdgcn_s_barrier();
    ++s; if (s == 3) s = 0;
  }

#pragma unroll
  for (int m = 0; m < 4; ++m) {
    int row0 = tile_m + wr * 64 + m * 16 + hi * 4;
#pragma unroll
    for (int n = 0; n < 4; ++n) {
      int col = tile_n + wc * 64 + n * 16 + r15;
      float bv = bias[col];
#pragma unroll
      for (int r = 0; r < 4; ++r)
        outp[(size_t)(row0 + r) * N_ + col] = acc[m][n][r] + bv;
    }
  }
}

// ---------------------------------------------------------------------------
// Flash attention, fully-swapped operands (unchanged from round 4 — passed).
__global__ __launch_bounds__(256, 2) void attn(
    const f16* __restrict__ q, const f16* __restrict__ k,
    const f16* __restrict__ vt, f16* __restrict__ x) {
  __shared__ f16 lK[2][64 * 64];
  __shared__ f16 lV[2][64 * 64];
  const int tid = threadIdx.x, lane = tid & 63, wid = tid >> 6;
  const int bh = blockIdx.y, b = bh >> 4, h = bh & 15;
  const int q0 = blockIdx.x * 256 + wid * 64;
  const int c15 = lane & 15, hi = lane >> 4;
  const int swr = (c15 & 7) << 4;
  const int swz = 8 * ((lane & 7) ^ (lane >> 3));
  const int lrow = lane >> 3;

  const f16* qb = q  + (size_t)b * S_ * N_ + h * DH_;
  const f16* kb = k  + (size_t)b * S_ * N_ + h * DH_;
  const f16* vb = vt + (size_t)bh * DH_ * S_;

  f16x8 qf[4][2];
#pragma unroll
  for (int qm = 0; qm < 4; ++qm)
#pragma unroll
    for (int kk = 0; kk < 2; ++kk)
      qf[qm][kk] = *(const f16x8*)(qb + (size_t)(q0 + qm * 16 + c15) * N_ + kk * 32 + hi * 8);

  f32x4 xa[4][4];
#pragma unroll
  for (int fn = 0; fn < 4; ++fn)
#pragma unroll
    for (int qm = 0; qm < 4; ++qm) xa[fn][qm] = (f32x4)(0.f);
  float rm[4], rl[4];
#pragma unroll
  for (int qm = 0; qm < 4; ++qm) { rm[qm] = -INFINITY; rl[qm] = 0.f; }

  auto STAGE = [&](int t, int buf) {
    int j0 = t * 64;
#pragma unroll
    for (int i = 0; i < 2; ++i) {
      int rb = wid * 16 + i * 8;
      async_cp16(kb + (size_t)(j0 + rb + lrow) * N_ + swz, &lK[buf][rb * 64]);
      async_cp16(vb + (size_t)(rb + lrow) * S_ + j0 + swz, &lV[buf][rb * 64]);
    }
  };

  STAGE(0, 0);
  __syncthreads();

  for (int t = 0; t < S_ / 64; ++t) {
    const int cur = t & 1;
    if (t < S_ / 64 - 1) STAGE(t + 1, cur ^ 1);

    f16x8 kf[4][2];
#pragma unroll
    for (int jn = 0; jn < 4; ++jn) {
      int rowe = (jn * 16 + c15) * 64;
#pragma unroll
      for (int kk = 0; kk < 2; ++kk)
        kf[jn][kk] = *(const f16x8*)&lK[cur][rowe + (((kk * 64 + hi * 16) ^ swr) >> 1)];
    }

    f16x8 bfrag[4][2];
#pragma unroll
    for (int qm = 0; qm < 4; ++qm) {
      f32x4 sq[4];
#pragma unroll
      for (int jn = 0; jn < 4; ++jn) sq[jn] = (f32x4)(0.f);
      __builtin_amdgcn_s_setprio(1);
#pragma unroll
      for (int kk = 0; kk < 2; ++kk)
#pragma unroll
        for (int jn = 0; jn < 4; ++jn)
          sq[jn] = __builtin_amdgcn_mfma_f32_16x16x32_f16(kf[jn][kk], qf[qm][kk], sq[jn], 0, 0, 0);
      __builtin_amdgcn_s_setprio(0);

      float mx = sq[0][0];
#pragma unroll
      for (int jn = 0; jn < 4; ++jn)
#pragma unroll
        for (int r = 0; r < 4; ++r) mx = fmaxf(mx, sq[jn][r]);
      mx = fmaxf(mx, __shfl_xor(mx, 16));
      mx = fmaxf(mx, __shfl_xor(mx, 32));

      float p[4][4], ts = 0.f;
      if (__all(mx - rm[qm] <= 8.0f)) {
#pragma unroll
        for (int jn = 0; jn < 4; ++jn)
#pragma unroll
          for (int r = 0; r < 4; ++r) {
            p[jn][r] = exp2_fast(sq[jn][r] - rm[qm]);
            ts += p[jn][r];
          }
        ts += __shfl_xor(ts, 16);
        ts += __shfl_xor(ts, 32);
        rl[qm] += ts;
      } else {
        float nm  = fmaxf(rm[qm], mx);
        float fac = exp2_fast(rm[qm] - nm);
        rm[qm] = nm;
#pragma unroll
        for (int jn = 0; jn < 4; ++jn)
#pragma unroll
          for (int r = 0; r < 4; ++r) {
            p[jn][r] = exp2_fast(sq[jn][r] - nm);
            ts += p[jn][r];
          }
        ts += __shfl_xor(ts, 16);
        ts += __shfl_xor(ts, 32);
        rl[qm] = rl[qm] * fac + ts;
#pragma unroll
        for (int fn = 0; fn < 4; ++fn)
#pragma unroll
          for (int r = 0; r < 4; ++r) xa[fn][qm][r] *= fac;
      }

      PK w[4][2];
#pragma unroll
      for (int jn = 0; jn < 4; ++jn)
#pragma unroll
        for (int hh = 0; hh < 2; ++hh)
          w[jn][hh].h2 = __floats2half2_rn(p[jn][2 * hh], p[jn][2 * hh + 1]);
#pragma unroll
      for (int kk = 0; kk < 2; ++kk) {
        H8 u;
        u.d[0] = w[2 * kk][0].v;     u.d[1] = w[2 * kk][1].v;
        u.d[2] = w[2 * kk + 1][0].v; u.d[3] = w[2 * kk + 1][1].v;
        bfrag[qm][kk] = u.v;
      }
    }

    __builtin_amdgcn_s_setprio(1);
#pragma unroll
    for (int kk = 0; kk < 2; ++kk)
#pragma unroll
      for (int fn = 0; fn < 4; ++fn) {
        int rowe = (fn * 16 + c15) * 64;
        H8 u;
        u.q[0] = *(const f16x4*)&lV[cur][rowe + (((kk * 64 + hi * 8) ^ swr) >> 1)];
        u.q[1] = *(const f16x4*)&lV[cur][rowe + (((kk * 64 + 32 + hi * 8) ^ swr) >> 1)];
#pragma unroll
        for (int qm = 0; qm < 4; ++qm)
          xa[fn][qm] = __builtin_amdgcn_mfma_f32_16x16x32_f16(u.v, bfrag[qm][kk], xa[fn][qm], 0, 0, 0);
      }
    __builtin_amdgcn_s_setprio(0);
    __syncthreads();
  }

  float inv[4];
#pragma unroll
  for (int qm = 0; qm < 4; ++qm) inv[qm] = 1.f / rl[qm];
#pragma unroll
  for (int qm = 0; qm < 4; ++qm) {
    size_t rowb = (size_t)(b * S_ + q0 + qm * 16 + c15) * N_ + h * DH_;
#pragma unroll
    for (int fn = 0; fn < 4; ++fn) {
      f16x4 o;
#pragma unroll
      for (int r = 0; r < 4; ++r) o[r] = (f16)(xa[fn][qm][r] * inv[qm]);
      *(f16x4*)(x + rowb + fn * 16 + hi * 4) = o;
    }
  }
}

// ---------------------------------------------------------------------------
extern "C" void kernel_launch(void* const* d_in, const int* in_sizes, int n_in,
                              void* d_out, int out_size, void* d_ws, size_t ws_size,
                              hipStream_t stream) {
  const float* inq  = (const float*)d_in[0];
  const float* inkv = (const float*)d_in[1];
  const float* Wq = (const float*)d_in[2];
  const float* bq = (const float*)d_in[3];
  const float* Wk = (const float*)d_in[4];
  const float* bk = (const float*)d_in[5];
  const float* Wv = (const float*)d_in[6];
  const float* bv = (const float*)d_in[7];
  const float* Wo = (const float*)d_in[8];
  const float* bo = (const float*)d_in[9];
  float* out = (float*)d_out;

  char* ws = (char*)d_ws;
  const size_t MB = 1024 * 1024;
  f16* h_inq  = (f16*)(ws + 0);         // 16MB, later reused as vt
  f16* h_inkv = (f16*)(ws + 16 * MB);   // 16MB, later reused as x
  f16* h_WqT  = (f16*)(ws + 32 * MB);   // WqT/WkT/WvT contiguous = WqkvT [3072][1024]
  f16* h_WkT  = (f16*)(ws + 34 * MB);
  f16* h_WvT  = (f16*)(ws + 36 * MB);
  f16* h_WoT  = (f16*)(ws + 38 * MB);
  f16* h_q    = (f16*)(ws + 40 * MB);
  f16* h_k    = (f16*)(ws + 56 * MB);
  f16* h_v    = (f16*)(ws + 72 * MB);
  f16* h_vt   = h_inq;                  // alias (inq dead after QKV GEMM)
  f16* h_x    = h_inkv;                 // alias (inkv dead after QKV GEMM)

  const int nIn = M_ * D_;
  cvt_f32_f16<<<nIn / 4 / 256, 256, 0, stream>>>(inq,  h_inq,  nIn / 4);
  cvt_f32_f16<<<nIn / 4 / 256, 256, 0, stream>>>(inkv, h_inkv, nIn / 4);
  transpose_w<<<dim3(32, 32, 4), dim3(32, 8), 0, stream>>>(
      Wq, Wk, Wv, Wo, h_WqT, h_WkT, h_WvT, h_WoT);
  // q scale folds 1/sqrt(DH) and log2(e) for the exp2-domain softmax
  const float qscale = 0.125f * 1.4426950408889634f;
  gemm_qkv8<<<768, 512, 0, stream>>>(h_inq, h_inkv, h_WqT,
                                     bq, bk, bv, qscale, h_q, h_k, h_v);
  transpose_v<<<dim3(S_ / 64, B_ * H_), 256, 0, stream>>>(h_v, h_vt);
  attn<<<dim3(S_ / 256, B_ * H_), 256, 0, stream>>>(h_q, h_k, h_vt, h_x);
  gemm_out8<<<256, 512, 0, stream>>>(h_x, h_WoT, bo, out);
}